// Round 9
// baseline (170.087 us; speedup 1.0000x reference)
//
#include <hip/hip_runtime.h>
#include <math.h>

// OnlineTripletLoss on MI355X — Round 9.
// R8: 161 us total, fused 93 us (MfmaUtil 23% = exactly the 20.6 us MFMA floor busy).
//     Decomposition: ~39 us VALU/DS (epilogue 5-step shuffle butterflies), rest = per-kk
//     barrier+vmcnt(0) drains with 1 block/CU; small kernels ~68 us.
// Changes:
//  (1) barrier-free K-loop: panel format IS the frag layout -> load frags directly from
//      global (global_load_dwordx4, lane->row), no LDS staging, no per-kk syncs;
//      compiler free to pipeline with fine-grained vmcnt. XCD swizzle keeps the
//      region working set (~3 MB) inside the 4 MB per-XCD L2.
//  (2) operand-swapped MFMA mfma(b,a,acc): rows->lanes, cols->regs; per-row reduction
//      = in-reg loop + ONE shfl_xor(32) (was 5-step butterfly chains).
//  (3) prep kernel fuses sq + init + panel build (4 launches -> 3).
// ws: sq[N] | hp[N] | hn_fall[N] | hn_semi[N] | bars[1024] | pad | pan[N*2D] f16

constexpr float MARGIN = 0.3f;

typedef _Float16 half8    __attribute__((ext_vector_type(8)));
typedef float    floatx16 __attribute__((ext_vector_type(16)));

// prep: 32 rows/block. thread (r = tid>>3, c8 = tid&7) handles kws c8+8*it.
// Builds pan[p][kc][r][8] (kc<64 hi, kc>=64 lo), sq, and per-row init.
__global__ __launch_bounds__(256)
void prep_kernel(const float* __restrict__ e, _Float16* __restrict__ pan,
                 float* __restrict__ sq, unsigned int* __restrict__ hp,
                 unsigned int* __restrict__ hn_fall, unsigned int* __restrict__ hn_semi,
                 unsigned int* __restrict__ bars, int N, int D) {
    if (blockIdx.x == 0 && threadIdx.x < 32) bars[threadIdx.x * 32] = 0u;
    const int r0  = blockIdx.x * 32;
    const int p   = r0 >> 7;
    const int rl  = r0 & 127;
    const int r   = threadIdx.x >> 3;
    const int c8  = threadIdx.x & 7;
    const int row = r0 + r;
    const float* er = e + (size_t)row * D;
    float s = 0.f;
    #pragma unroll
    for (int it = 0; it < 8; ++it) {
        const int kw = c8 + it * 8;
        const float4 x0 = *(const float4*)&er[kw * 8];
        const float4 x1 = *(const float4*)&er[kw * 8 + 4];
        const float xv[8] = {x0.x, x0.y, x0.z, x0.w, x1.x, x1.y, x1.z, x1.w};
        half8 hi, lo;
        #pragma unroll
        for (int j = 0; j < 8; ++j) {
            _Float16 h = (_Float16)xv[j];
            hi[j] = h;
            lo[j] = (_Float16)(xv[j] - (float)h);
            s += xv[j] * xv[j];
        }
        *(half8*)&pan[((size_t)(p * 128 + kw) * 128 + rl + r) * 8]      = hi;
        *(half8*)&pan[((size_t)(p * 128 + 64 + kw) * 128 + rl + r) * 8] = lo;
    }
    s += __shfl_down(s, 4, 8);
    s += __shfl_down(s, 2, 8);
    s += __shfl_down(s, 1, 8);
    if (c8 == 0) {
        sq[row]      = s;
        hp[row]      = 0u;           // max identity (dist >= 0)
        hn_fall[row] = 0u;
        hn_semi[row] = 0x7f800000u;  // +inf (min identity)
    }
}

// Fused two-phase kernel, barrier-free K-loop. Tile 128x128, 4 waves (2x2) of 64x64.
// Operand-swapped MFMA: accT[bj][ai]: cols in regs, rows in lanes.
__global__ __launch_bounds__(256, 4)
void fused_kernel(const _Float16* __restrict__ pan, const int* __restrict__ labels,
                  const float* __restrict__ sq,
                  unsigned int* __restrict__ hp,
                  unsigned int* __restrict__ hn_fall,
                  unsigned int* __restrict__ hn_semi,
                  unsigned int* __restrict__ bars,
                  int N, int D, unsigned int nrowblocks) {
    __shared__ float sq_r[128], sq_c[128], hp_r[128];
    __shared__ int   lab_r[128], lab_c[128];

    const int tid  = threadIdx.x;
    const int lane = tid & 63;
    const int wave = tid >> 6;
    const int wr = (wave >> 1) * 64;     // wave row offset
    const int wc = (wave & 1) * 64;      // wave col offset
    const int mrow = lane & 31;
    const int half_id = lane >> 5;

    // XCD swizzle: 8 regions of 8(px) x 16(py) over the 32x32 tile grid (~3MB/XCD L2)
    const int j  = blockIdx.x & 7;
    const int i  = blockIdx.x >> 3;      // 0..127
    const int px = (j & 3) * 8 + (i & 7);
    const int py = (j >> 2) * 16 + (i >> 3);
    const int rowBase = py * 128;
    const int colBase = px * 128;

    if (tid < 128) {
        sq_r[tid]  = sq[rowBase + tid];
        lab_r[tid] = labels[rowBase + tid];
    } else {
        int t = tid - 128;
        sq_c[t]  = sq[colBase + t];
        lab_c[t] = labels[colBase + t];
    }
    __syncthreads();

    floatx16 acc[2][2];   // acc[bj][ai]: col-block bj (regs), row-block ai (lanes)
    #pragma unroll
    for (int a = 0; a < 2; ++a)
        #pragma unroll
        for (int b = 0; b < 2; ++b)
            #pragma unroll
            for (int r = 0; r < 16; ++r) acc[a][b][r] = 0.f;

    // frag base pointers: pan[p][kc][row]: lane -> row (mrow), kc-half (half_id)
    const size_t aBase = ((size_t)(py * 128 + half_id) * 128 + wr + mrow) * 8;
    const size_t bBase = ((size_t)(px * 128 + half_id) * 128 + wc + mrow) * 8;
    const size_t loOff = (size_t)64 * 128 * 8;      // +64 kc planes
    const size_t rstep = (size_t)2 * 128 * 8;       // +2 kc planes per k16 step

    #pragma unroll 4
    for (int s = 0; s < 32; ++s) {
        const _Float16* ga = pan + aBase + (size_t)s * rstep;
        const _Float16* gb = pan + bBase + (size_t)s * rstep;
        const half8 ah0 = *(const half8*)(ga);
        const half8 ah1 = *(const half8*)(ga + 32 * 8);
        const half8 bh0 = *(const half8*)(gb);
        const half8 bh1 = *(const half8*)(gb + 32 * 8);
        const half8 al0 = *(const half8*)(ga + loOff);
        const half8 al1 = *(const half8*)(ga + loOff + 32 * 8);
        const half8 bl0 = *(const half8*)(gb + loOff);
        const half8 bl1 = *(const half8*)(gb + loOff + 32 * 8);
        // swapped operands: D[col(reg)][row(lane)]
        acc[0][0] = __builtin_amdgcn_mfma_f32_32x32x16_f16(bh0, ah0, acc[0][0], 0, 0, 0);
        acc[0][1] = __builtin_amdgcn_mfma_f32_32x32x16_f16(bh0, ah1, acc[0][1], 0, 0, 0);
        acc[1][0] = __builtin_amdgcn_mfma_f32_32x32x16_f16(bh1, ah0, acc[1][0], 0, 0, 0);
        acc[1][1] = __builtin_amdgcn_mfma_f32_32x32x16_f16(bh1, ah1, acc[1][1], 0, 0, 0);
        acc[0][0] = __builtin_amdgcn_mfma_f32_32x32x16_f16(bl0, ah0, acc[0][0], 0, 0, 0);
        acc[0][1] = __builtin_amdgcn_mfma_f32_32x32x16_f16(bl0, ah1, acc[0][1], 0, 0, 0);
        acc[1][0] = __builtin_amdgcn_mfma_f32_32x32x16_f16(bl1, ah0, acc[1][0], 0, 0, 0);
        acc[1][1] = __builtin_amdgcn_mfma_f32_32x32x16_f16(bl1, ah1, acc[1][1], 0, 0, 0);
        acc[0][0] = __builtin_amdgcn_mfma_f32_32x32x16_f16(bh0, al0, acc[0][0], 0, 0, 0);
        acc[0][1] = __builtin_amdgcn_mfma_f32_32x32x16_f16(bh0, al1, acc[0][1], 0, 0, 0);
        acc[1][0] = __builtin_amdgcn_mfma_f32_32x32x16_f16(bh1, al0, acc[1][0], 0, 0, 0);
        acc[1][1] = __builtin_amdgcn_mfma_f32_32x32x16_f16(bh1, al1, acc[1][1], 0, 0, 0);
    }

    // ---- epilogue: rows in lanes. row(ai) = wr + ai*32 + mrow ----
    // col(bj,r) = wc + bj*32 + (r&3) + 8*(r>>2) + 4*half_id
    float sqr[2]; int labr[2];
    #pragma unroll
    for (int ai = 0; ai < 2; ++ai) {
        sqr[ai]  = sq_r[wr + ai * 32 + mrow];
        labr[ai] = lab_r[wr + ai * 32 + mrow];
    }

    // ---- phase 1: hp / hn_fall ----
    #pragma unroll
    for (int ai = 0; ai < 2; ++ai) {
        float vp = 0.f, vn = 0.f;
        #pragma unroll
        for (int bj = 0; bj < 2; ++bj) {
            #pragma unroll
            for (int r = 0; r < 16; ++r) {
                const int c = wc + bj * 32 + (r & 3) + 8 * (r >> 2) + 4 * half_id;
                float d = sqrtf(fmaxf(sqr[ai] + sq_c[c] - 2.0f * acc[bj][ai][r], 1e-12f));
                const bool pos = (labr[ai] == lab_c[c]);
                vp = fmaxf(vp, pos ? d : 0.f);
                vn = fmaxf(vn, pos ? 0.f : d);
            }
        }
        vp = fmaxf(vp, __shfl_xor(vp, 32, 64));   // merge col halves
        vn = fmaxf(vn, __shfl_xor(vn, 32, 64));
        if (half_id == 0) {
            atomicMax(&hp[rowBase + wr + ai * 32 + mrow],      __float_as_uint(vp));
            atomicMax(&hn_fall[rowBase + wr + ai * 32 + mrow], __float_as_uint(vn));
        }
    }

    // ---- per-row-panel barrier: the 32 blocks sharing py ----
    __syncthreads();
    unsigned int* ctr = &bars[py * 32];
    if (tid == 0) {
        __threadfence();
        atomicAdd(ctr, 1u);
        while (__hip_atomic_load(ctr, __ATOMIC_ACQUIRE, __HIP_MEMORY_SCOPE_AGENT)
               < nrowblocks)
            __builtin_amdgcn_s_sleep(32);
    }
    __syncthreads();
    if (tid < 128)
        hp_r[tid] = __uint_as_float(__hip_atomic_load(&hp[rowBase + tid],
                                    __ATOMIC_RELAXED, __HIP_MEMORY_SCOPE_AGENT));
    __syncthreads();

    // ---- phase 2: hn_semi = min{d : neg, d > hp} ----
    #pragma unroll
    for (int ai = 0; ai < 2; ++ai) {
        const float hpv = hp_r[wr + ai * 32 + mrow];
        float vm = __builtin_inff();
        #pragma unroll
        for (int bj = 0; bj < 2; ++bj) {
            #pragma unroll
            for (int r = 0; r < 16; ++r) {
                const int c = wc + bj * 32 + (r & 3) + 8 * (r >> 2) + 4 * half_id;
                float d = sqrtf(fmaxf(sqr[ai] + sq_c[c] - 2.0f * acc[bj][ai][r], 1e-12f));
                const bool cand = (labr[ai] != lab_c[c]) && (d > hpv);
                vm = fminf(vm, cand ? d : __builtin_inff());
            }
        }
        vm = fminf(vm, __shfl_xor(vm, 32, 64));
        if (half_id == 0)
            atomicMin(&hn_semi[rowBase + wr + ai * 32 + mrow], __float_as_uint(vm));
    }
}

__global__ void final_kernel(const unsigned int* __restrict__ hp,
                             const unsigned int* __restrict__ hn_fall,
                             const unsigned int* __restrict__ hn_semi,
                             float* __restrict__ out, int N) {
    __shared__ float ssum[256];
    __shared__ int   scnt[256];
    __shared__ int   sany[256];
    int any = 0;
    for (int i = threadIdx.x; i < N; i += 256) {
        float h  = __uint_as_float(hp[i]);
        float hs = __uint_as_float(hn_semi[i]);
        any |= (hs < h + MARGIN) ? 1 : 0;   // exists semi-hard pair in this row
    }
    sany[threadIdx.x] = any;
    __syncthreads();
    for (int s = 128; s; s >>= 1) {
        if (threadIdx.x < (unsigned)s) sany[threadIdx.x] |= sany[threadIdx.x + s];
        __syncthreads();
    }
    const bool has_semi = sany[0] != 0;
    float sum = 0.f; int valid = 0;
    for (int i = threadIdx.x; i < N; i += 256) {
        float h  = __uint_as_float(hp[i]);
        float hn = has_semi ? __uint_as_float(hn_semi[i]) : __uint_as_float(hn_fall[i]);
        float t  = fmaxf(h - hn + MARGIN, 0.f);
        if (!(t > 0.f)) t = 0.f;            // -inf guard (hn=+inf rows)
        sum += t;
        valid += (t > 0.f) ? 1 : 0;
    }
    ssum[threadIdx.x] = sum; scnt[threadIdx.x] = valid;
    __syncthreads();
    for (int s = 128; s; s >>= 1) {
        if (threadIdx.x < (unsigned)s) {
            ssum[threadIdx.x] += ssum[threadIdx.x + s];
            scnt[threadIdx.x] += scnt[threadIdx.x + s];
        }
        __syncthreads();
    }
    if (threadIdx.x == 0) {
        float total = ssum[0]; int v = scnt[0];
        out[0] = (v > 0) ? (total / (float)v) : (total / (float)N);
    }
}

extern "C" void kernel_launch(void* const* d_in, const int* in_sizes, int n_in,
                              void* d_out, int out_size, void* d_ws, size_t ws_size,
                              hipStream_t stream) {
    const float* e      = (const float*)d_in[0];
    const int*   labels = (const int*)d_in[1];
    const int N = in_sizes[1];
    const int D = in_sizes[0] / N;
    float* out = (float*)d_out;

    float*        sq      = (float*)d_ws;
    unsigned int* hp      = (unsigned int*)d_ws + N;
    unsigned int* hn_fall = hp + N;
    unsigned int* hn_semi = hn_fall + N;
    unsigned int* bars    = hn_semi + N;     // 32 counters, 128B-spaced (1024 words)

    const size_t small_bytes = ((size_t)(4 * N + 1024) * 4 + 255) & ~(size_t)255;
    _Float16* pan = (_Float16*)((char*)d_ws + small_bytes);

    prep_kernel<<<N / 32, 256, 0, stream>>>(e, pan, sq, hp, hn_fall, hn_semi, bars, N, D);

    const int nt = N / 128;                  // 32x32 tile grid, XCD-swizzled 1D launch
    fused_kernel<<<nt * nt, 256, 0, stream>>>(pan, labels, sq, hp, hn_fall, hn_semi,
                                              bars, N, D, (unsigned)nt);
    final_kernel<<<1, 256, 0, stream>>>(hp, hn_fall, hn_semi, out, N);
}

// Round 10
// 139.081 us; speedup vs baseline: 1.2229x; 1.2229x over previous
//
#include <hip/hip_runtime.h>
#include <math.h>

// OnlineTripletLoss on MI355X — Round 10.
// R9: barrier-free global-frag K-loop REGRESSED (93 -> 107 us): raw-latency path loses
//     to staged LDS. R8's staged dbuf 256x256 loop (93 us) remains the best core, but
//     at 1 block/CU every per-kk sync idles the whole CU.
// Changes:
//  (1) staged double-buffered K-loop at 256x128 / 512 thr / grid 512 = 2 blocks/CU
//      (48 KB dbuf + meta; threads/LDS/VGPR all allow 2 co-resident) -> cross-block
//      stall overlap (m114).
//  (2) swapped-operand MFMA epilogue (R9-verified): rows in lanes, one shfl_xor(32).
//  (3) 2 launches: prep + fused (final folded in via last-block done-counter).
// ws: sq[N] | hp[N] | hn_fall[N] | hn_semi[N] | bars[1024] | pad | pan[N*2D] f16

constexpr float MARGIN = 0.3f;

typedef _Float16 half8    __attribute__((ext_vector_type(8)));
typedef float    floatx16 __attribute__((ext_vector_type(16)));

#define GLD_LDS16(gp, lp)                                                              \
    __builtin_amdgcn_global_load_lds(                                                  \
        (const __attribute__((address_space(1))) void*)(gp),                           \
        (__attribute__((address_space(3))) void*)(lp), 16, 0, 0)

// prep: 32 rows/block; builds pan[p][kc][r][8] (kc<64 hi, kc>=64 lo), sq, init, bars.
__global__ __launch_bounds__(256)
void prep_kernel(const float* __restrict__ e, _Float16* __restrict__ pan,
                 float* __restrict__ sq, unsigned int* __restrict__ hp,
                 unsigned int* __restrict__ hn_fall, unsigned int* __restrict__ hn_semi,
                 unsigned int* __restrict__ bars, int N, int D) {
    if (blockIdx.x == 0 && threadIdx.x < 32) bars[threadIdx.x * 32] = 0u;
    const int r0  = blockIdx.x * 32;
    const int p   = r0 >> 7;
    const int rl  = r0 & 127;
    const int r   = threadIdx.x >> 3;
    const int c8  = threadIdx.x & 7;
    const int row = r0 + r;
    const float* er = e + (size_t)row * D;
    float s = 0.f;
    #pragma unroll
    for (int it = 0; it < 8; ++it) {
        const int kw = c8 + it * 8;
        const float4 x0 = *(const float4*)&er[kw * 8];
        const float4 x1 = *(const float4*)&er[kw * 8 + 4];
        const float xv[8] = {x0.x, x0.y, x0.z, x0.w, x1.x, x1.y, x1.z, x1.w};
        half8 hi, lo;
        #pragma unroll
        for (int j = 0; j < 8; ++j) {
            _Float16 h = (_Float16)xv[j];
            hi[j] = h;
            lo[j] = (_Float16)(xv[j] - (float)h);
            s += xv[j] * xv[j];
        }
        *(half8*)&pan[((size_t)(p * 128 + kw) * 128 + rl + r) * 8]      = hi;
        *(half8*)&pan[((size_t)(p * 128 + 64 + kw) * 128 + rl + r) * 8] = lo;
    }
    s += __shfl_down(s, 4, 8);
    s += __shfl_down(s, 2, 8);
    s += __shfl_down(s, 1, 8);
    if (c8 == 0) {
        sq[row]      = s;
        hp[row]      = 0u;           // max identity (dist >= 0)
        hn_fall[row] = 0u;
        hn_semi[row] = 0x7f800000u;  // +inf (min identity)
    }
}

// Fused kernel: tile 256(rows) x 128(cols), 512 thr = 8 waves (4x2) of 64x64.
// Double-buffered DMA staging (BK=16), swapped-operand MFMA, per-row-panel barrier,
// last-block final reduction.
__global__ __launch_bounds__(512, 4)
void fused_kernel(const _Float16* __restrict__ pan, const int* __restrict__ labels,
                  const float* __restrict__ sq,
                  unsigned int* __restrict__ hp,
                  unsigned int* __restrict__ hn_fall,
                  unsigned int* __restrict__ hn_semi,
                  unsigned int* __restrict__ bars,
                  float* __restrict__ out,
                  int N, int D, unsigned int nrowblocks, unsigned int nblocks) {
    // per buffer (12288 halves = 24 KB): A[kcl(4)][r(256)][8] | B[kcl(4)][r(128)][8]
    // kcl: 0,1 = hi k-chunks (2kk, 2kk+1); 2,3 = lo k-chunks.
    __shared__ __attribute__((aligned(16))) _Float16 S[2][12288];   // 48 KB
    __shared__ float sq_r[256], sq_c[128], hp_r[256];
    __shared__ int   lab_r[256], lab_c[128];
    __shared__ int   lastflag;

    const int tid  = threadIdx.x;
    const int lane = tid & 63;
    const int wave = tid >> 6;            // 0..7
    const int wr = (wave >> 1) * 64;      // 0,64,128,192
    const int wc = (wave & 1) * 64;       // 0,64
    const int mrow = lane & 31;
    const int half_id = lane >> 5;

    // XCD swizzle: 8 regions of 8(px) x 8(py) over the 32 x 16 tile grid
    const int j  = blockIdx.x & 7;
    const int i  = blockIdx.x >> 3;       // 0..63
    const int px = (j & 3) * 8 + (i & 7);         // 0..31 (128-col tiles)
    const int py = (j >> 2) * 8 + (i >> 3);       // 0..15 (256-row tiles)
    const int rowBase = py * 256;
    const int colBase = px * 128;

    if (tid < 256) {
        sq_r[tid]  = sq[rowBase + tid];
        lab_r[tid] = labels[rowBase + tid];
    } else if (tid < 384) {
        const int t = tid - 256;
        sq_c[t]  = sq[colBase + t];
        lab_c[t] = labels[colBase + t];
    }

    floatx16 acc[2][2];   // acc[bj][ai]: cols in regs (bj), rows in lanes (ai)
    #pragma unroll
    for (int a = 0; a < 2; ++a)
        #pragma unroll
        for (int b = 0; b < 2; ++b)
            #pragma unroll
            for (int r = 0; r < 16; ++r) acc[a][b][r] = 0.f;

    // staging: 24 slabs of 1KB per stage (A 16, B 8); wave w issues slabs 3w..3w+2
    auto stage = [&](int b, int kkv) {
        #pragma unroll
        for (int t = 0; t < 3; ++t) {
            const int s = wave * 3 + t;
            int kcl, p, row0, lofs;
            if (s < 16) {            // A slab: kcl = s>>2, row-quarter rq = s&3
                const int rq = s & 3;
                kcl  = s >> 2;
                p    = 2 * py + (rq >> 1);
                row0 = (rq & 1) * 64;
                lofs = (kcl * 256 + rq * 64) * 8;
            } else {                 // B slab
                const int u = s - 16;
                kcl  = u >> 1;
                p    = px;
                row0 = (u & 1) * 64;
                lofs = 8192 + (kcl * 128 + row0) * 8;
            }
            const int kc = (kcl < 2) ? (2 * kkv + kcl) : (64 + 2 * kkv + (kcl - 2));
            const _Float16* g = pan + ((size_t)(p * 128 + kc) * 128 + row0 + lane) * 8;
            GLD_LDS16(g, &S[b][lofs]);
        }
    };

    stage(0, 0);                       // prologue prefetch

    #pragma unroll 1
    for (int kk = 0; kk < 32; ++kk) {
        const int b = kk & 1;
        __syncthreads();               // drains this wave's DMAs (issued 1 phase ago)
        if (kk + 1 < 32) stage(b ^ 1, kk + 1);
        const int rA = wr + mrow, cB = wc + mrow;
        const half8 ah0 = *(const half8*)&S[b][(half_id * 256 + rA) * 8];
        const half8 ah1 = *(const half8*)&S[b][(half_id * 256 + rA + 32) * 8];
        const half8 al0 = *(const half8*)&S[b][((2 + half_id) * 256 + rA) * 8];
        const half8 al1 = *(const half8*)&S[b][((2 + half_id) * 256 + rA + 32) * 8];
        const half8 bh0 = *(const half8*)&S[b][8192 + (half_id * 128 + cB) * 8];
        const half8 bh1 = *(const half8*)&S[b][8192 + (half_id * 128 + cB + 32) * 8];
        const half8 bl0 = *(const half8*)&S[b][8192 + ((2 + half_id) * 128 + cB) * 8];
        const half8 bl1 = *(const half8*)&S[b][8192 + ((2 + half_id) * 128 + cB + 32) * 8];
        // swapped operands: D[col(reg)][row(lane)] ; dot = hi.hi + lo.hi + hi.lo
        acc[0][0] = __builtin_amdgcn_mfma_f32_32x32x16_f16(bh0, ah0, acc[0][0], 0, 0, 0);
        acc[0][1] = __builtin_amdgcn_mfma_f32_32x32x16_f16(bh0, ah1, acc[0][1], 0, 0, 0);
        acc[1][0] = __builtin_amdgcn_mfma_f32_32x32x16_f16(bh1, ah0, acc[1][0], 0, 0, 0);
        acc[1][1] = __builtin_amdgcn_mfma_f32_32x32x16_f16(bh1, ah1, acc[1][1], 0, 0, 0);
        acc[0][0] = __builtin_amdgcn_mfma_f32_32x32x16_f16(bl0, ah0, acc[0][0], 0, 0, 0);
        acc[0][1] = __builtin_amdgcn_mfma_f32_32x32x16_f16(bl0, ah1, acc[0][1], 0, 0, 0);
        acc[1][0] = __builtin_amdgcn_mfma_f32_32x32x16_f16(bl1, ah0, acc[1][0], 0, 0, 0);
        acc[1][1] = __builtin_amdgcn_mfma_f32_32x32x16_f16(bl1, ah1, acc[1][1], 0, 0, 0);
        acc[0][0] = __builtin_amdgcn_mfma_f32_32x32x16_f16(bh0, al0, acc[0][0], 0, 0, 0);
        acc[0][1] = __builtin_amdgcn_mfma_f32_32x32x16_f16(bh0, al1, acc[0][1], 0, 0, 0);
        acc[1][0] = __builtin_amdgcn_mfma_f32_32x32x16_f16(bh1, al0, acc[1][0], 0, 0, 0);
        acc[1][1] = __builtin_amdgcn_mfma_f32_32x32x16_f16(bh1, al1, acc[1][1], 0, 0, 0);
    }

    // ---- epilogue: rows in lanes. row(ai) = wr + ai*32 + mrow ----
    float sqr[2]; int labr[2];
    #pragma unroll
    for (int ai = 0; ai < 2; ++ai) {
        sqr[ai]  = sq_r[wr + ai * 32 + mrow];
        labr[ai] = lab_r[wr + ai * 32 + mrow];
    }

    // ---- phase 1: hp / hn_fall ----
    #pragma unroll
    for (int ai = 0; ai < 2; ++ai) {
        float vp = 0.f, vn = 0.f;
        #pragma unroll
        for (int bj = 0; bj < 2; ++bj) {
            #pragma unroll
            for (int r = 0; r < 16; ++r) {
                const int c = wc + bj * 32 + (r & 3) + 8 * (r >> 2) + 4 * half_id;
                float d = sqrtf(fmaxf(sqr[ai] + sq_c[c] - 2.0f * acc[bj][ai][r], 1e-12f));
                const bool pos = (labr[ai] == lab_c[c]);
                vp = fmaxf(vp, pos ? d : 0.f);
                vn = fmaxf(vn, pos ? 0.f : d);
            }
        }
        vp = fmaxf(vp, __shfl_xor(vp, 32, 64));   // merge col halves
        vn = fmaxf(vn, __shfl_xor(vn, 32, 64));
        if (half_id == 0) {
            atomicMax(&hp[rowBase + wr + ai * 32 + mrow],      __float_as_uint(vp));
            atomicMax(&hn_fall[rowBase + wr + ai * 32 + mrow], __float_as_uint(vn));
        }
    }

    // ---- per-row-panel barrier: the 32 blocks sharing py (all blocks co-resident) ----
    __syncthreads();
    unsigned int* ctr = &bars[py * 32];
    if (tid == 0) {
        __threadfence();
        atomicAdd(ctr, 1u);
        while (__hip_atomic_load(ctr, __ATOMIC_ACQUIRE, __HIP_MEMORY_SCOPE_AGENT)
               < nrowblocks)
            __builtin_amdgcn_s_sleep(32);
    }
    __syncthreads();
    if (tid < 256)
        hp_r[tid] = __uint_as_float(__hip_atomic_load(&hp[rowBase + tid],
                                    __ATOMIC_RELAXED, __HIP_MEMORY_SCOPE_AGENT));
    __syncthreads();

    // ---- phase 2: hn_semi = min{d : neg, d > hp} ----
    #pragma unroll
    for (int ai = 0; ai < 2; ++ai) {
        const float hpv = hp_r[wr + ai * 32 + mrow];
        float vm = __builtin_inff();
        #pragma unroll
        for (int bj = 0; bj < 2; ++bj) {
            #pragma unroll
            for (int r = 0; r < 16; ++r) {
                const int c = wc + bj * 32 + (r & 3) + 8 * (r >> 2) + 4 * half_id;
                float d = sqrtf(fmaxf(sqr[ai] + sq_c[c] - 2.0f * acc[bj][ai][r], 1e-12f));
                const bool cand = (labr[ai] != lab_c[c]) && (d > hpv);
                vm = fminf(vm, cand ? d : __builtin_inff());
            }
        }
        vm = fminf(vm, __shfl_xor(vm, 32, 64));
        if (half_id == 0)
            atomicMin(&hn_semi[rowBase + wr + ai * 32 + mrow], __float_as_uint(vm));
    }

    // ---- last-block final reduction ----
    __syncthreads();
    if (tid == 0) {
        __threadfence();
        unsigned int old = atomicAdd(&bars[992], 1u);
        lastflag = (old == nblocks - 1) ? 1 : 0;
    }
    __syncthreads();
    if (!lastflag) return;
    if (tid == 0) __threadfence();      // acquire before cross-XCD reads
    __syncthreads();

    float* FS = (float*)&S[0][0];       // 512 sums
    int*   IC = (int*)(FS + 512);       // 512 counts
    int*   IA = IC + 512;               // 512 any-flags
    int any = 0;
    for (int r = tid; r < N; r += 512) {
        float h  = __uint_as_float(__hip_atomic_load(&hp[r],      __ATOMIC_RELAXED, __HIP_MEMORY_SCOPE_AGENT));
        float hs = __uint_as_float(__hip_atomic_load(&hn_semi[r], __ATOMIC_RELAXED, __HIP_MEMORY_SCOPE_AGENT));
        any |= (hs < h + MARGIN) ? 1 : 0;
    }
    IA[tid] = any;
    __syncthreads();
    for (int s = 256; s; s >>= 1) {
        if (tid < s) IA[tid] |= IA[tid + s];
        __syncthreads();
    }
    const bool has_semi = IA[0] != 0;
    float sum = 0.f; int valid = 0;
    for (int r = tid; r < N; r += 512) {
        float h  = __uint_as_float(__hip_atomic_load(&hp[r], __ATOMIC_RELAXED, __HIP_MEMORY_SCOPE_AGENT));
        float hn = has_semi
            ? __uint_as_float(__hip_atomic_load(&hn_semi[r], __ATOMIC_RELAXED, __HIP_MEMORY_SCOPE_AGENT))
            : __uint_as_float(__hip_atomic_load(&hn_fall[r], __ATOMIC_RELAXED, __HIP_MEMORY_SCOPE_AGENT));
        float t = fmaxf(h - hn + MARGIN, 0.f);
        if (!(t > 0.f)) t = 0.f;        // -inf guard (hn=+inf rows)
        sum += t;
        valid += (t > 0.f) ? 1 : 0;
    }
    FS[tid] = sum; IC[tid] = valid;
    __syncthreads();
    for (int s = 256; s; s >>= 1) {
        if (tid < s) { FS[tid] += FS[tid + s]; IC[tid] += IC[tid + s]; }
        __syncthreads();
    }
    if (tid == 0) {
        float total = FS[0]; int v = IC[0];
        out[0] = (v > 0) ? (total / (float)v) : (total / (float)N);
    }
}

extern "C" void kernel_launch(void* const* d_in, const int* in_sizes, int n_in,
                              void* d_out, int out_size, void* d_ws, size_t ws_size,
                              hipStream_t stream) {
    const float* e      = (const float*)d_in[0];
    const int*   labels = (const int*)d_in[1];
    const int N = in_sizes[1];
    const int D = in_sizes[0] / N;
    float* out = (float*)d_out;

    float*        sq      = (float*)d_ws;
    unsigned int* hp      = (unsigned int*)d_ws + N;
    unsigned int* hn_fall = hp + N;
    unsigned int* hn_semi = hn_fall + N;
    unsigned int* bars    = hn_semi + N;     // 32 counters (128B-spaced) + done @992

    const size_t small_bytes = ((size_t)(4 * N + 1024) * 4 + 255) & ~(size_t)255;
    _Float16* pan = (_Float16*)((char*)d_ws + small_bytes);

    prep_kernel<<<N / 32, 256, 0, stream>>>(e, pan, sq, hp, hn_fall, hn_semi, bars, N, D);

    const int ntx = N / 128, nty = N / 256;  // 32 x 16 tiles = 512 blocks = 2/CU
    fused_kernel<<<ntx * nty, 512, 0, stream>>>(pan, labels, sq, hp, hn_fall, hn_semi,
                                                bars, out, N, D,
                                                (unsigned)ntx, (unsigned)(ntx * nty));
}